// Round 5
// baseline (154.499 us; speedup 1.0000x reference)
//
#include <hip/hip_runtime.h>

#define N_NODES_C   524288
#define N_EDGES_C   786432
#define NUM_GRAPHS_C 8192
#define NT 16          // NUM_NODE_TYPES
#define NODE_DIM_C 256
#define EDGE_DIM_C 128
#define HDIM 384       // NODE_DIM + EDGE_DIM
#define KC 48          // folded inner dim: 16 (node) + 32 (edge)

// R15: 3-kernel pipeline (kr -> km -> k3), ~90 us of dur_us is fixed harness
// reset traffic (256-MB ws poison + memset train), so kernel-side budget is
// ~54 us; this round removes k0 (fused into kr), the 16-MB em8 round-trip
// (scaled atomicAdd into 1-MB em, zeroed by kr), and 2 launch gaps.
// XCD slicing retained: h_node = 32 MiB = 8 x 4 MiB = one L2 slice per XCD
// (slice = idx>>16); edge wave (g,slice) placed so blk%8 == slice == XCD
// (m09 heuristic, correctness-independent); records compacted per
// (slice,endpoint,graph) by kr with LDS-only atomics.
#define FOLD_BLOCKS 72             // ceil(KC*HDIM/256)
#define NODE_BLOCKS 2048           // slice-aligned: r&7 = slice octant
#define EDGE_BLOCKS 16384          // wave = (graph, slice); blk%8 = slice
#define NODE_BASE   FOLD_BLOCKS    // 72 % 8 == 0
#define EDGE_BASE   (FOLD_BLOCKS + NODE_BLOCKS)   // 2120 % 8 == 0
#define TOTAL_BLOCKS (FOLD_BLOCKS + NODE_BLOCKS + EDGE_BLOCKS)

// ---------------- workspace layout (bytes, 64-aligned) ----------------
#define WS_NM    0                  // float[8192*16]   512 KB
#define WS_EM    524288             // float[8192*32]   1 MB (means, atomic)
#define WS_WC    1572864            // float[48*384]    73728 B
#define WS_NS    1646592            // int[8193]
#define WS_BOFF  1679424            // int[8192*16] bin start offsets, 512 KB
#define WS_ECNT  2203712            // int[8192] edge counts per graph
#define WS_REC   2236480            // int[1572864] node-index records, 6 MB

__device__ __forceinline__ void f4_add(float4& a, const float4 v) {
    a.x += v.x; a.y += v.y; a.z += v.z; a.w += v.w;
}

__device__ __forceinline__ void f4_shfl_xor_add(float4& a, int mask) {
    a.x += __shfl_xor(a.x, mask, 64);
    a.y += __shfl_xor(a.y, mask, 64);
    a.z += __shfl_xor(a.z, mask, 64);
    a.w += __shfl_xor(a.w, mask, 64);
}

__device__ __forceinline__ int lower_bound_i32(const int* __restrict__ a, int n, int key) {
    int lo = 0, hi = n;
    while (lo < hi) {
        int mid = (lo + hi) >> 1;
        if (a[mid] < key) lo = mid + 1; else hi = mid;
    }
    return lo;
}

// In-wave segment bounds: lanes 0-31 chase start(g), lanes 32-63 chase end(g)
// concurrently, then shuffle-broadcast (R0-verified).
__device__ __forceinline__ void wave_seg_bounds(const int* __restrict__ b, int n,
                                                int g, int lane, int& s, int& e) {
    int key = g + ((lane >= 32) ? 1 : 0);
    int lo = lower_bound_i32(b, n, key);
    s = __shfl(lo, 0, 64);
    e = __shfl(lo, 32, 64);
}

// kr: fused prep. 2048 blocks x 256 = 524288 threads.
//  - thread i: node-boundary detect -> nstart (bnode sorted).
//  - tid<128: zero this block's 4 graphs' em rows (4*32 floats).
//  - wave w: graph g = blk*4+w. In-wave binary search of bedge -> (s,e);
//    LDS histogram of the graph's edges into 16 (slice,endpoint) bins;
//    in-wave scan of 16 counts; LDS-cursor placement of node-index records
//    into the graph-private region [2s,2e) of rec. No global atomics.
__global__ __launch_bounds__(256) void kr_build(
    const int* __restrict__ bnode, const int* __restrict__ bedge,
    const int* __restrict__ esrc, const int* __restrict__ edst,
    int* __restrict__ rec, int* __restrict__ binoff,
    int* __restrict__ ecnt, int* __restrict__ nstart, float* __restrict__ em) {
    int tid = threadIdx.x, blk = blockIdx.x;
    int i = blk * 256 + tid;
    {   // node segment bounds (i covers all N_NODES exactly)
        int g0 = bnode[i];
        int hi = (i + 1 < N_NODES_C) ? bnode[i + 1] : NUM_GRAPHS_C;
        if (i == 0) for (int g = 0; g <= g0; ++g) nstart[g] = 0;
        for (int g = g0 + 1; g <= hi; ++g) nstart[g] = i + 1;
    }
    if (tid < 128) em[blk * 128 + tid] = 0.f;   // this block's 4 em rows

    int wave = tid >> 6, lane = tid & 63;
    int g = blk * 4 + wave;
    int s, e;
    wave_seg_bounds(bedge, N_EDGES_C, g, lane, s, e);
    if (lane == 0) ecnt[g] = e - s;

    __shared__ int lcnt[4][16];
    __shared__ int lcur[4][16];
    if (lane < 16) lcnt[wave][lane] = 0;        // wave-lockstep ordering
    for (int q = s + lane; q < e; q += 64) {
        int a = esrc[q];
        atomicAdd(&lcnt[wave][((a >> 16) << 1) + 0], 1);
        int b = edst[q];
        atomicAdd(&lcnt[wave][((b >> 16) << 1) + 1], 1);
    }
    int c = (lane < 16) ? lcnt[wave][lane] : 0;
    int incl = c;
    #pragma unroll
    for (int d = 1; d < 16; d <<= 1) {
        int v = __shfl_up(incl, d, 64);
        if (lane >= d) incl += v;
    }
    int excl = incl - c;
    if (lane < 16) {
        lcur[wave][lane] = excl;                // local cursor
        binoff[g * 16 + lane] = 2 * s + excl;   // absolute bin start
    }
    for (int q = s + lane; q < e; q += 64) {
        int a = esrc[q];
        int pa = atomicAdd(&lcur[wave][((a >> 16) << 1) + 0], 1);
        rec[2 * s + pa] = a;
        int b = edst[q];
        int pb = atomicAdd(&lcur[wave][((b >> 16) << 1) + 1], 1);
        rec[2 * s + pb] = b;
    }
}

// KM mega-kernel:
//  blocks [0,72):             Wc fold: Wc[k][j] = embedder_row(k) . W1 col j.
//  blocks [NODE_BASE,+2048):  node means; r&7 = slice octant (g>>10) so the
//     sequential h_node stream primes the owning XCD's L2.
//  blocks [EDGE_BASE,+16384): edge partials; wave = (g, slice); two compact
//     record lists (bins 2*slice, 2*slice+1, adjacent); rows L2-local;
//     inv-scaled atomicAdd into em (slice partials sum to the mean).
__global__ __launch_bounds__(256) void km_mega(
    const float* __restrict__ h_node,
    const int* __restrict__ nstart, const int* __restrict__ binoff,
    const int* __restrict__ ecnt, const int* __restrict__ rec,
    const float* __restrict__ Wn, const float* __restrict__ We,
    const float* __restrict__ W1,
    float* __restrict__ nm, float* __restrict__ em, float* __restrict__ Wc) {
    int blk  = blockIdx.x;
    int wave = threadIdx.x >> 6;
    int lane = threadIdx.x & 63;
    const float4* h4 = (const float4*)h_node;
    const float4 z4 = make_float4(0.f, 0.f, 0.f, 0.f);

    if (blk < FOLD_BLOCKS) {
        // ---- weight fold ----
        int o = blk * 256 + threadIdx.x;        // 0..18431 (= KC*HDIM)
        if (o >= KC * HDIM) return;
        int k = o / HDIM, j = o % HDIM;
        float acc = 0.f;
        if (k < NT) {
            const float* wr = &Wn[k * NODE_DIM_C];
            #pragma unroll 16
            for (int kk = 0; kk < NODE_DIM_C; ++kk)
                acc = fmaf(wr[kk], W1[(size_t)kk * HDIM + j], acc);
        } else {
            const float* wr = &We[(k - NT) * EDGE_DIM_C];
            #pragma unroll 16
            for (int kk = 0; kk < EDGE_DIM_C; ++kk)
                acc = fmaf(wr[kk], W1[(size_t)(NODE_DIM_C + kk) * HDIM + j], acc);
        }
        Wc[o] = acc;
    } else if (blk < EDGE_BASE) {
        // ---- node means (slice-aligned placement) ----
        int r = blk - NODE_BASE;
        int s8 = r & 7;                 // target XCD == slice octant
        int g  = s8 * 1024 + (r >> 3) * 4 + wave;
        int s = nstart[g], e = nstart[g + 1];
        int row_off = lane >> 2;   // 0..15
        int quad    = lane & 3;    // 0..3
        float4 a0 = z4, a1 = z4;
        int i = s + row_off;
        for (; i + 16 < e; i += 32) {
            float4 v0 = h4[(size_t)i * 4 + quad];
            float4 v1 = h4[(size_t)(i + 16) * 4 + quad];
            f4_add(a0, v0);
            f4_add(a1, v1);
        }
        if (i < e) f4_add(a0, h4[(size_t)i * 4 + quad]);
        f4_add(a0, a1);
        f4_shfl_xor_add(a0, 4);
        f4_shfl_xor_add(a0, 8);
        f4_shfl_xor_add(a0, 16);
        f4_shfl_xor_add(a0, 32);
        if (row_off == 0) {
            float inv = 1.f / fmaxf((float)(e - s), 1.f);
            ((float4*)nm)[(size_t)g * 4 + quad] =
                make_float4(a0.x * inv, a0.y * inv, a0.z * inv, a0.w * inv);
        }
    } else {
        // ---- edge partial sums (compacted slice-local gather) ----
        int r     = blk - EDGE_BASE;
        int slice = r & 7;                      // == blk%8 == XCD (heuristic)
        int g     = (r >> 3) * 4 + wave;
        int b16   = g * 16 + slice * 2;
        int base0 = binoff[b16];                // src list start
        int base1 = binoff[b16 + 1];            // dst list start
        int cnt   = ecnt[g];
        int end1  = (slice == 7) ? binoff[g * 16] + 2 * cnt : binoff[b16 + 2];
        int slot = lane >> 3;          // 0..7 record slot
        int p    = (lane >> 2) & 1;    // 0=src 1=dst
        int quad = lane & 3;           // 16 B quarter of the 64-B row
        int st = p ? base1 : base0;
        int en = p ? end1  : base1;
        int cmax = max(base1 - base0, end1 - base1);
        int T = (cmax + 7) >> 3;       // wave-uniform trips, 8 recs/list/iter
        float4 acc = z4;
        int i = st + slot;
        int idx = (i < en) ? rec[i] : -1;
        for (int t = 1; t < T; ++t) {
            int i2 = i + 8;
            int nx = (i2 < en) ? rec[i2] : -1;   // prefetch next record
            if (idx >= 0) f4_add(acc, h4[(size_t)idx * 4 + quad]);
            idx = nx; i = i2;
        }
        if (idx >= 0) f4_add(acc, h4[(size_t)idx * 4 + quad]);
        // reduce over slot (lane bits 3..5)
        f4_shfl_xor_add(acc, 8);
        f4_shfl_xor_add(acc, 16);
        f4_shfl_xor_add(acc, 32);
        if (slot == 0) {
            // scale partial by inv(cnt) so the 8 slice partials sum to the mean
            float inv = 1.f / fmaxf((float)cnt, 1.f);
            // em row = 32 floats: quads 0..3 = src half, 4..7 = dst half
            float* dst = &em[(size_t)g * 32 + p * 16 + quad * 4];
            atomicAdd(dst + 0, acc.x * inv);
            atomicAdd(dst + 1, acc.y * inv);
            atomicAdd(dst + 2, acc.z * inv);
            atomicAdd(dst + 3, acc.w * inv);
        }
    }
}

// K3: fused MLP.  f[g] = [nm(g) | em(g)]  (48 dims, em already normalized)
// pred[g] = relu(f[g] @ Wc + b1) . W2 + b2
#define GPB 16
__global__ __launch_bounds__(HDIM) void k3_mlp(
    const float* __restrict__ nm, const float* __restrict__ em,
    const float* __restrict__ Wc, const float* __restrict__ b1,
    const float* __restrict__ W2, const float* __restrict__ b2,
    float* __restrict__ pred) {
    int j = threadIdx.x;
    float wc[KC];
    #pragma unroll
    for (int k = 0; k < KC; ++k) wc[k] = Wc[k * HDIM + j];
    float b1j = b1[j], w2j = W2[j], b20 = b2[0];

    __shared__ float fs[GPB][KC];
    __shared__ float part[GPB][6];
    int g0 = blockIdx.x * GPB;
    #pragma unroll
    for (int t = j; t < GPB * KC; t += HDIM) {
        int g = t / KC, k = t % KC;
        fs[g][k] = (k < NT) ? nm[(size_t)(g0 + g) * NT + k]
                            : em[(size_t)(g0 + g) * 32 + (k - NT)];
    }
    __syncthreads();

    int wave = j >> 6, lane = j & 63;
    for (int g = 0; g < GPB; ++g) {
        float z = b1j;
        #pragma unroll
        for (int k = 0; k < KC; ++k) z = fmaf(fs[g][k], wc[k], z);
        z = fmaxf(z, 0.f);
        float p = z * w2j;
        #pragma unroll
        for (int off = 32; off > 0; off >>= 1) p += __shfl_down(p, off, 64);
        if (lane == 0) part[g][wave] = p;
    }
    __syncthreads();
    if (j < GPB) {
        float sacc = b20;
        #pragma unroll
        for (int w = 0; w < 6; ++w) sacc += part[j][w];
        pred[g0 + j] = sacc;
    }
}

extern "C" void kernel_launch(void* const* d_in, const int* in_sizes, int n_in,
                              void* d_out, int out_size, void* d_ws, size_t ws_size,
                              hipStream_t stream) {
    const float* h_node     = (const float*)d_in[0];
    // d_in[1] = pos_node (unused)
    const int*   batch_node = (const int*)d_in[2];
    const int*   edge_index = (const int*)d_in[3];   // [2, E] row-major
    const int*   batch_edge = (const int*)d_in[4];
    const float* W_node     = (const float*)d_in[5];
    const float* W_edge     = (const float*)d_in[6];
    const float* W1         = (const float*)d_in[7];
    const float* b1         = (const float*)d_in[8];
    const float* W2         = (const float*)d_in[9];
    const float* b2         = (const float*)d_in[10];
    float* pred = (float*)d_out;

    char* ws = (char*)d_ws;
    float* nm     = (float*)(ws + WS_NM);
    float* em     = (float*)(ws + WS_EM);
    float* Wc     = (float*)(ws + WS_WC);
    int*   nstart = (int*)(ws + WS_NS);
    int*   binoff = (int*)(ws + WS_BOFF);
    int*   ecnt   = (int*)(ws + WS_ECNT);
    int*   rec    = (int*)(ws + WS_REC);

    const int* esrc = edge_index;
    const int* edst = edge_index + N_EDGES_C;

    // kr: fused prep (node bounds + em zero + per-graph record compaction)
    kr_build<<<NUM_GRAPHS_C / 4, 256, 0, stream>>>(
        batch_node, batch_edge, esrc, edst, rec, binoff, ecnt, nstart, em);
    // KM: fold (72) + slice-aligned node means (2048) + compacted edge gather (16384)
    km_mega <<<TOTAL_BLOCKS, 256, 0, stream>>>(
        h_node, nstart, binoff, ecnt, rec, W_node, W_edge, W1, nm, em, Wc);
    // K3: fused folded MLP
    k3_mlp  <<<NUM_GRAPHS_C / GPB, HDIM, 0, stream>>>(
        nm, em, Wc, b1, W2, b2, pred);
}

// Round 6
// 150.026 us; speedup vs baseline: 1.0298x; 1.0298x over previous
//
#include <hip/hip_runtime.h>

#define N_NODES_C   524288
#define N_EDGES_C   786432
#define NUM_GRAPHS_C 8192
#define NT 16          // NUM_NODE_TYPES
#define NODE_DIM_C 256
#define EDGE_DIM_C 128
#define HDIM 384       // NODE_DIM + EDGE_DIM
#define KC 48          // folded inner dim: 16 (node) + 32 (edge)

// R16: recombination of proven pieces.
//  - XCD slicing (R12/R14-proven: FETCH ~= compulsory): slice = idx>>16,
//    edge wave (g,slice) placed so blk%8 == slice == XCD.
//  - NO global atomics (R15 post-mortem: cross-XCD f32 atomicAdd write-through
//    cost +33 MB HBM WRITE and ~10 us): slice partials to em8[g][slice][32],
//    folded in k3 with contiguous 1-KB/graph reads.
//  - int4 desc per (g,slice): edge-wave bounds = ONE dwordx4 load instead of
//    3-4 dependent scalar loads (kr outputs are HBM-cold by gather time).
//  - fold lives in kr; km = 2048 node blocks (prime L2, fill residency first)
//    then 16384 edge blocks.
#define KR_GRAPH_BLOCKS 2048
#define KR_FOLD_BLOCKS  72
#define KR_BLOCKS (KR_GRAPH_BLOCKS + KR_FOLD_BLOCKS)
#define NODE_BLOCKS 2048           // slice-aligned: blk&7 = slice octant
#define EDGE_BLOCKS 16384          // wave = (graph, slice); blk%8 = slice
#define EDGE_BASE   NODE_BLOCKS    // 2048 % 8 == 0
#define KM_BLOCKS   (NODE_BLOCKS + EDGE_BLOCKS)

// ---------------- workspace layout (bytes, 64-aligned) ----------------
#define WS_NM    0                  // float[8192*16]        512 KB
#define WS_EM8   524288             // float[8192][8][32]    8 MB
#define WS_WC    8912896            // float[48*384]         73728 B
#define WS_NS    8986624            // int[8193]
#define WS_DESC  9019456            // int4[8192*8]          1 MB
#define WS_ECNT  10068032           // int[8192]
#define WS_REC   10100800           // int[1572864]          6 MB

__device__ __forceinline__ void f4_add(float4& a, const float4 v) {
    a.x += v.x; a.y += v.y; a.z += v.z; a.w += v.w;
}

__device__ __forceinline__ void f4_shfl_xor_add(float4& a, int mask) {
    a.x += __shfl_xor(a.x, mask, 64);
    a.y += __shfl_xor(a.y, mask, 64);
    a.z += __shfl_xor(a.z, mask, 64);
    a.w += __shfl_xor(a.w, mask, 64);
}

__device__ __forceinline__ int lower_bound_i32(const int* __restrict__ a, int n, int key) {
    int lo = 0, hi = n;
    while (lo < hi) {
        int mid = (lo + hi) >> 1;
        if (a[mid] < key) lo = mid + 1; else hi = mid;
    }
    return lo;
}

// In-wave segment bounds: lanes 0-31 chase start(g), lanes 32-63 chase end(g)
// concurrently, then shuffle-broadcast (R0-verified).
__device__ __forceinline__ void wave_seg_bounds(const int* __restrict__ b, int n,
                                                int g, int lane, int& s, int& e) {
    int key = g + ((lane >= 32) ? 1 : 0);
    int lo = lower_bound_i32(b, n, key);
    s = __shfl(lo, 0, 64);
    e = __shfl(lo, 32, 64);
}

// kr: fused prep. blocks [0,2048): per-graph record build; [2048,+72): Wc fold.
//  Graph block (4 waves, 1 graph/wave): thread i node-boundary-detect -> nstart;
//  wave: in-wave bsearch of bedge -> (s,e); LDS histogram into 16
//  (slice,endpoint) bins; in-wave scan; desc int4 per slice; LDS-cursor record
//  placement into graph-private region [2s,2e) of rec. No global atomics.
__global__ __launch_bounds__(256) void kr_build(
    const int* __restrict__ bnode, const int* __restrict__ bedge,
    const int* __restrict__ esrc, const int* __restrict__ edst,
    const float* __restrict__ Wn, const float* __restrict__ We,
    const float* __restrict__ W1,
    int* __restrict__ rec, int4* __restrict__ desc,
    int* __restrict__ ecnt, int* __restrict__ nstart, float* __restrict__ Wc) {
    int tid = threadIdx.x, blk = blockIdx.x;

    if (blk >= KR_GRAPH_BLOCKS) {
        // ---- weight fold ----
        int o = (blk - KR_GRAPH_BLOCKS) * 256 + tid;    // 0..18431 (= KC*HDIM)
        if (o >= KC * HDIM) return;
        int k = o / HDIM, j = o % HDIM;
        float acc = 0.f;
        if (k < NT) {
            const float* wr = &Wn[k * NODE_DIM_C];
            #pragma unroll 16
            for (int kk = 0; kk < NODE_DIM_C; ++kk)
                acc = fmaf(wr[kk], W1[(size_t)kk * HDIM + j], acc);
        } else {
            const float* wr = &We[(k - NT) * EDGE_DIM_C];
            #pragma unroll 16
            for (int kk = 0; kk < EDGE_DIM_C; ++kk)
                acc = fmaf(wr[kk], W1[(size_t)(NODE_DIM_C + kk) * HDIM + j], acc);
        }
        Wc[o] = acc;
        return;
    }

    int i = blk * 256 + tid;
    {   // node segment bounds (2048*256 threads cover N_NODES exactly)
        int g0 = bnode[i];
        int hi = (i + 1 < N_NODES_C) ? bnode[i + 1] : NUM_GRAPHS_C;
        if (i == 0) for (int g = 0; g <= g0; ++g) nstart[g] = 0;
        for (int g = g0 + 1; g <= hi; ++g) nstart[g] = i + 1;
    }

    int wave = tid >> 6, lane = tid & 63;
    int g = blk * 4 + wave;
    int s, e;
    wave_seg_bounds(bedge, N_EDGES_C, g, lane, s, e);
    int cnt = e - s;
    if (lane == 0) ecnt[g] = cnt;

    __shared__ int lcnt[4][16];
    __shared__ int lcur[4][16];
    if (lane < 16) lcnt[wave][lane] = 0;        // wave-lockstep DS ordering
    for (int q = s + lane; q < e; q += 64) {
        int a = esrc[q];
        atomicAdd(&lcnt[wave][((a >> 16) << 1) + 0], 1);
        int b = edst[q];
        atomicAdd(&lcnt[wave][((b >> 16) << 1) + 1], 1);
    }
    int c = (lane < 16) ? lcnt[wave][lane] : 0;
    int incl = c;
    #pragma unroll
    for (int d = 1; d < 16; d <<= 1) {
        int v = __shfl_up(incl, d, 64);
        if (lane >= d) incl += v;
    }
    int excl = incl - c;
    if (lane < 16) lcur[wave][lane] = excl;     // local cursor
    // desc[(g,slice)] = {src_start, dst_start, dst_end, cnt} (absolute offsets)
    int i0 = (lane < 8) ? 2 * lane : 0;
    int i1 = (lane < 8) ? 2 * lane + 1 : 0;
    int i2 = (lane < 7) ? 2 * lane + 2 : 0;
    int b0 = __shfl(excl, i0, 64);
    int b1 = __shfl(excl, i1, 64);
    int e1 = __shfl(excl, i2, 64);
    if (lane < 8) {
        int e1a = (lane == 7) ? 2 * s + 2 * cnt : 2 * s + e1;
        desc[(g << 3) + lane] = make_int4(2 * s + b0, 2 * s + b1, e1a, cnt);
    }
    for (int q = s + lane; q < e; q += 64) {
        int a = esrc[q];
        int pa = atomicAdd(&lcur[wave][((a >> 16) << 1) + 0], 1);
        rec[2 * s + pa] = a;
        int b = edst[q];
        int pb = atomicAdd(&lcur[wave][((b >> 16) << 1) + 1], 1);
        rec[2 * s + pb] = b;
    }
}

// KM mega-kernel:
//  blocks [0,2048):           node means; blk&7 = slice octant (g>>10) so the
//     sequential h_node stream primes the owning XCD's L2; these 2048 blocks
//     exactly fill 8-blocks/CU residency before any edge block dispatches.
//  blocks [2048,+16384):      edge partials; wave = (g, slice); bounds from one
//     int4 desc load; rows L2-local; plain float4 store to em8[g][slice].
__global__ __launch_bounds__(256) void km_mega(
    const float* __restrict__ h_node,
    const int* __restrict__ nstart, const int4* __restrict__ desc,
    const int* __restrict__ rec,
    float* __restrict__ nm, float* __restrict__ em8) {
    int blk  = blockIdx.x;
    int wave = threadIdx.x >> 6;
    int lane = threadIdx.x & 63;
    const float4* h4 = (const float4*)h_node;
    const float4 z4 = make_float4(0.f, 0.f, 0.f, 0.f);

    if (blk < EDGE_BASE) {
        // ---- node means (slice-aligned placement) ----
        int s8 = blk & 7;               // target XCD == slice octant
        int g  = s8 * 1024 + (blk >> 3) * 4 + wave;
        int s = nstart[g], e = nstart[g + 1];
        int row_off = lane >> 2;   // 0..15
        int quad    = lane & 3;    // 0..3
        float4 a0 = z4, a1 = z4;
        int i = s + row_off;
        for (; i + 16 < e; i += 32) {
            float4 v0 = h4[(size_t)i * 4 + quad];
            float4 v1 = h4[(size_t)(i + 16) * 4 + quad];
            f4_add(a0, v0);
            f4_add(a1, v1);
        }
        if (i < e) f4_add(a0, h4[(size_t)i * 4 + quad]);
        f4_add(a0, a1);
        f4_shfl_xor_add(a0, 4);
        f4_shfl_xor_add(a0, 8);
        f4_shfl_xor_add(a0, 16);
        f4_shfl_xor_add(a0, 32);
        if (row_off == 0) {
            float inv = 1.f / fmaxf((float)(e - s), 1.f);
            ((float4*)nm)[(size_t)g * 4 + quad] =
                make_float4(a0.x * inv, a0.y * inv, a0.z * inv, a0.w * inv);
        }
    } else {
        // ---- edge partial sums (compacted slice-local gather) ----
        int r     = blk - EDGE_BASE;
        int slice = r & 7;                      // == blk%8 == XCD (heuristic)
        int g     = (r >> 3) * 4 + wave;
        int4 d    = desc[(g << 3) + slice];     // one load: {s0, s1, e1, cnt}
        int slot = lane >> 3;          // 0..7 record slot
        int p    = (lane >> 2) & 1;    // 0=src 1=dst
        int quad = lane & 3;           // 16 B quarter of the 64-B row
        int st = p ? d.y : d.x;
        int en = p ? d.z : d.y;
        int cmax = max(d.y - d.x, d.z - d.y);
        int T = (cmax + 7) >> 3;       // wave-uniform trips, 8 recs/list/iter
        float4 acc = z4;
        int i = st + slot;
        int idx = (i < en) ? rec[i] : -1;
        for (int t = 1; t < T; ++t) {
            int i2 = i + 8;
            int nx = (i2 < en) ? rec[i2] : -1;   // prefetch next record
            if (idx >= 0) f4_add(acc, h4[(size_t)idx * 4 + quad]);
            idx = nx; i = i2;
        }
        if (idx >= 0) f4_add(acc, h4[(size_t)idx * 4 + quad]);
        // reduce over slot (lane bits 3..5)
        f4_shfl_xor_add(acc, 8);
        f4_shfl_xor_add(acc, 16);
        f4_shfl_xor_add(acc, 32);
        if (slot == 0) {
            // em8[g][slice] row = 32 floats: quads 0..3 src half, 4..7 dst half
            ((float4*)em8)[((size_t)(g * 8 + slice)) * 8 + p * 4 + quad] = acc;
        }
    }
}

// K3: fused MLP.  f[g] = [nm(g) | (Σ_s em8[g][s]) / ecnt(g)]  (48 dims)
// pred[g] = relu(f[g] @ Wc + b1) . W2 + b2
#define GPB 16
__global__ __launch_bounds__(HDIM) void k3_mlp(
    const float* __restrict__ nm, const float* __restrict__ em8,
    const int* __restrict__ ecnt,
    const float* __restrict__ Wc, const float* __restrict__ b1,
    const float* __restrict__ W2, const float* __restrict__ b2,
    float* __restrict__ pred) {
    int j = threadIdx.x;
    float wc[KC];
    #pragma unroll
    for (int k = 0; k < KC; ++k) wc[k] = Wc[k * HDIM + j];
    float b1j = b1[j], w2j = W2[j], b20 = b2[0];

    __shared__ float fs[GPB][KC];
    __shared__ float part[GPB][6];
    int g0 = blockIdx.x * GPB;
    for (int t = j; t < GPB * KC; t += HDIM) {
        int g = t / KC, k = t % KC;
        int G = g0 + g;
        float val;
        if (k < NT) {
            val = nm[(size_t)G * NT + k];
        } else {
            float ssum = 0.f;
            #pragma unroll
            for (int s = 0; s < 8; ++s)
                ssum += em8[((size_t)(G * 8 + s)) * 32 + (k - NT)];
            val = ssum / fmaxf((float)ecnt[G], 1.f);
        }
        fs[g][k] = val;
    }
    __syncthreads();

    int wave = j >> 6, lane = j & 63;
    for (int g = 0; g < GPB; ++g) {
        float z = b1j;
        #pragma unroll
        for (int k = 0; k < KC; ++k) z = fmaf(fs[g][k], wc[k], z);
        z = fmaxf(z, 0.f);
        float p = z * w2j;
        #pragma unroll
        for (int off = 32; off > 0; off >>= 1) p += __shfl_down(p, off, 64);
        if (lane == 0) part[g][wave] = p;
    }
    __syncthreads();
    if (j < GPB) {
        float sacc = b20;
        #pragma unroll
        for (int w = 0; w < 6; ++w) sacc += part[j][w];
        pred[g0 + j] = sacc;
    }
}

extern "C" void kernel_launch(void* const* d_in, const int* in_sizes, int n_in,
                              void* d_out, int out_size, void* d_ws, size_t ws_size,
                              hipStream_t stream) {
    const float* h_node     = (const float*)d_in[0];
    // d_in[1] = pos_node (unused)
    const int*   batch_node = (const int*)d_in[2];
    const int*   edge_index = (const int*)d_in[3];   // [2, E] row-major
    const int*   batch_edge = (const int*)d_in[4];
    const float* W_node     = (const float*)d_in[5];
    const float* W_edge     = (const float*)d_in[6];
    const float* W1         = (const float*)d_in[7];
    const float* b1         = (const float*)d_in[8];
    const float* W2         = (const float*)d_in[9];
    const float* b2         = (const float*)d_in[10];
    float* pred = (float*)d_out;

    char* ws = (char*)d_ws;
    float* nm     = (float*)(ws + WS_NM);
    float* em8    = (float*)(ws + WS_EM8);
    float* Wc     = (float*)(ws + WS_WC);
    int*   nstart = (int*)(ws + WS_NS);
    int4*  desc   = (int4*)(ws + WS_DESC);
    int*   ecnt   = (int*)(ws + WS_ECNT);
    int*   rec    = (int*)(ws + WS_REC);

    const int* esrc = edge_index;
    const int* edst = edge_index + N_EDGES_C;

    // kr: fused prep (node bounds + record compaction + desc + Wc fold)
    kr_build<<<KR_BLOCKS, 256, 0, stream>>>(
        batch_node, batch_edge, esrc, edst, W_node, W_edge, W1,
        rec, desc, ecnt, nstart, Wc);
    // KM: slice-aligned node means (2048) then compacted edge gather (16384)
    km_mega <<<KM_BLOCKS, 256, 0, stream>>>(
        h_node, nstart, desc, rec, nm, em8);
    // K3: fold partials + normalize + MLP
    k3_mlp  <<<NUM_GRAPHS_C / GPB, HDIM, 0, stream>>>(
        nm, em8, ecnt, Wc, b1, W2, b2, pred);
}